// Round 1
// baseline (180.142 us; speedup 1.0000x reference)
//
#include <hip/hip_runtime.h>

#define WIN   7
#define TILE  32
#define INTW  38            // TILE + WIN - 1
#define IMH   640
#define IMW   640
#define OH    634           // IMH - WIN + 1
#define OW    634
#define NB    64
#define NTIL  20            // ceil(634/32)

__global__ __launch_bounds__(256) void ssim_partial(
    const float* __restrict__ X, const float* __restrict__ Y,
    const float* __restrict__ dr, double* __restrict__ partial)
{
    __shared__ float sX[INTW][INTW + 2];   // pad to 40 floats/row
    __shared__ float sY[INTW][INTW + 2];
    __shared__ float hx [INTW][TILE];
    __shared__ float hy [INTW][TILE];
    __shared__ float hxx[INTW][TILE];
    __shared__ float hyy[INTW][TILE];
    __shared__ float hxy[INTW][TILE];

    const int tid = threadIdx.x;
    const int b  = blockIdx.z;
    const int r0 = blockIdx.y * TILE;
    const int c0 = blockIdx.x * TILE;
    const float* Xb = X + (size_t)b * IMH * IMW;
    const float* Yb = Y + (size_t)b * IMH * IMW;

    // ---- Phase 1: global -> LDS (38x38 halo tile, clamped at image edge;
    // clamped values are only ever consumed by masked-out output pixels) ----
    for (int i = tid; i < INTW * INTW; i += 256) {
        int r = i / INTW, c = i - r * INTW;
        int gr = r0 + r; if (gr > IMH - 1) gr = IMH - 1;
        int gc = c0 + c; if (gc > IMW - 1) gc = IMW - 1;
        float xv = Xb[gr * IMW + gc];
        float yv = Yb[gr * IMW + gc];
        sX[r][c] = xv;
        sY[r][c] = yv;
    }
    __syncthreads();

    // ---- Phase 2: horizontal 7-tap row sums for the 5 moments ----
    for (int i = tid; i < INTW * TILE; i += 256) {
        int r = i >> 5, c = i & 31;
        float ax = 0.f, ay = 0.f, axx = 0.f, ayy = 0.f, axy = 0.f;
        #pragma unroll
        for (int k = 0; k < WIN; ++k) {
            float x = sX[r][c + k], y = sY[r][c + k];
            ax  += x;     ay  += y;
            axx += x * x; ayy += y * y; axy += x * y;
        }
        hx [r][c] = ax;  hy [r][c] = ay;
        hxx[r][c] = axx; hyy[r][c] = ayy; hxy[r][c] = axy;
    }
    __syncthreads();

    const float d  = dr[b];
    const float C1 = (0.01f * d) * (0.01f * d);
    const float C2 = (0.03f * d) * (0.03f * d);
    const float inv_np   = 1.0f / 49.0f;
    const float cov_norm = 49.0f / 48.0f;

    double acc = 0.0;
    #pragma unroll
    for (int p = 0; p < 4; ++p) {
        int idx = tid + p * 256;        // 1024 outputs / 256 threads
        int r = idx >> 5, c = idx & 31;
        float sx = 0.f, sy = 0.f, sxx = 0.f, syy = 0.f, sxy = 0.f;
        #pragma unroll
        for (int k = 0; k < WIN; ++k) {
            sx  += hx [r + k][c]; sy  += hy [r + k][c];
            sxx += hxx[r + k][c]; syy += hyy[r + k][c]; sxy += hxy[r + k][c];
        }
        if (r0 + r < OH && c0 + c < OW) {
            float ux  = sx  * inv_np, uy  = sy  * inv_np;
            float uxx = sxx * inv_np, uyy = syy * inv_np, uxy = sxy * inv_np;
            float vx  = cov_norm * (uxx - ux * ux);
            float vy  = cov_norm * (uyy - uy * uy);
            float vxy = cov_norm * (uxy - ux * uy);
            float A1 = 2.f * ux * uy + C1;
            float A2 = 2.f * vxy + C2;
            float B1 = ux * ux + uy * uy + C1;
            float B2 = vx + vy + C2;
            acc += (double)((A1 * A2) / (B1 * B2));
        }
    }

    // ---- Phase 4: block reduction of doubles ----
    for (int off = 32; off > 0; off >>= 1)
        acc += __shfl_down(acc, off, 64);
    __shared__ double sred[4];
    if ((tid & 63) == 0) sred[tid >> 6] = acc;
    __syncthreads();
    if (tid == 0) {
        double t = sred[0] + sred[1] + sred[2] + sred[3];
        partial[((size_t)blockIdx.z * NTIL + blockIdx.y) * NTIL + blockIdx.x] = t;
    }
}

__global__ __launch_bounds__(256) void ssim_reduce(
    const double* __restrict__ partial, int n, float* __restrict__ out)
{
    double acc = 0.0;
    for (int i = threadIdx.x; i < n; i += 256) acc += partial[i];
    for (int off = 32; off > 0; off >>= 1)
        acc += __shfl_down(acc, off, 64);
    __shared__ double sred[4];
    if ((threadIdx.x & 63) == 0) sred[threadIdx.x >> 6] = acc;
    __syncthreads();
    if (threadIdx.x == 0) {
        double denom = (double)NB * (double)OH * (double)OW;
        out[0] = (float)(sred[0] + sred[1] + sred[2] + sred[3] ? 0.0 : 0.0, // (no-op guard removed below)
                 (sred[0] + sred[1] + sred[2] + sred[3]) / denom);
    }
}

extern "C" void kernel_launch(void* const* d_in, const int* in_sizes, int n_in,
                              void* d_out, int out_size, void* d_ws, size_t ws_size,
                              hipStream_t stream) {
    const float* X  = (const float*)d_in[0];
    const float* Y  = (const float*)d_in[1];
    const float* dr = (const float*)d_in[2];
    // d_in[3] is w = ones/49; constant-folded into inv_np in the kernel.
    double* partial = (double*)d_ws;   // 25600 * 8 B = 200 KB scratch

    dim3 grid(NTIL, NTIL, NB);
    ssim_partial<<<grid, 256, 0, stream>>>(X, Y, dr, partial);
    ssim_reduce<<<1, 256, 0, stream>>>(partial, NTIL * NTIL * NB, (float*)d_out);
}

// Round 2
// 119.377 us; speedup vs baseline: 1.5090x; 1.5090x over previous
//
#include <hip/hip_runtime.h>

#define WIN   7
#define TILE  32
#define INTW  38            // TILE + WIN - 1
#define IMH   640
#define IMW   640
#define OH    634           // IMH - WIN + 1
#define OW    634
#define NB    64
#define NTIL  20            // ceil(634/32)
#define SSTR  41            // sSD row stride (float2) — padded vs 40
#define HSTR  33            // hmo row stride (float4) — padded vs 32

__global__ __launch_bounds__(256) void ssim_partial(
    const float* __restrict__ X, const float* __restrict__ Y,
    const float* __restrict__ dr, double* __restrict__ partial)
{
    // (s,d) = (x+y, x-y) interleaved; 4 moments (Ss, Sd, Sss, Sdd) as float4
    __shared__ float2 sSD[INTW * SSTR];   // 38*41*8  = 12464 B
    __shared__ float4 hmo[INTW * HSTR];   // 38*33*16 = 20064 B  (total 32528 B -> 5 blocks/CU)

    const int tid = threadIdx.x;
    const int b  = blockIdx.z;
    const int r0 = blockIdx.y * TILE;
    const int c0 = blockIdx.x * TILE;
    const float* Xb = X + (size_t)b * IMH * IMW;
    const float* Yb = Y + (size_t)b * IMH * IMW;

    // ---- Phase 1: global -> LDS, compute (s,d) on the fly ----
    if (c0 + 40 <= IMW) {
        // fast path: load 40 cols as 10 float4 per row (aligned: c0 % 32 == 0)
        for (int i = tid; i < INTW * 10; i += 256) {
            int r = i / 10, j = i - r * 10;
            int gr = r0 + r; if (gr > IMH - 1) gr = IMH - 1;
            const float4 xv = *(const float4*)(Xb + (size_t)gr * IMW + c0 + 4 * j);
            const float4 yv = *(const float4*)(Yb + (size_t)gr * IMW + c0 + 4 * j);
            int base = r * SSTR + 4 * j;
            sSD[base + 0] = make_float2(xv.x + yv.x, xv.x - yv.x);
            sSD[base + 1] = make_float2(xv.y + yv.y, xv.y - yv.y);
            sSD[base + 2] = make_float2(xv.z + yv.z, xv.z - yv.z);
            sSD[base + 3] = make_float2(xv.w + yv.w, xv.w - yv.w);
        }
    } else {
        // last column tile: scalar with column clamp (clamped values only feed
        // masked-out outputs)
        for (int i = tid; i < INTW * INTW; i += 256) {
            int r = i / INTW, c = i - r * INTW;
            int gr = r0 + r; if (gr > IMH - 1) gr = IMH - 1;
            int gc = c0 + c; if (gc > IMW - 1) gc = IMW - 1;
            float x = Xb[(size_t)gr * IMW + gc];
            float y = Yb[(size_t)gr * IMW + gc];
            sSD[r * SSTR + c] = make_float2(x + y, x - y);
        }
    }
    __syncthreads();

    // ---- Phase 2: horizontal 7-tap sums of (s, d, s^2, d^2), sliding over
    // 4-column groups. 38 rows x 8 groups = 304 items. ----
    for (int i = tid; i < INTW * 8; i += 256) {
        int r = i >> 3, g = i & 7;
        int c = 4 * g;
        int base = r * SSTR + c;
        float4 m = make_float4(0.f, 0.f, 0.f, 0.f);
        #pragma unroll
        for (int k = 0; k < WIN; ++k) {
            float2 v = sSD[base + k];
            m.x += v.x; m.y += v.y;
            m.z += v.x * v.x; m.w += v.y * v.y;
        }
        hmo[r * HSTR + c] = m;
        #pragma unroll
        for (int s = 1; s < 4; ++s) {
            float2 a = sSD[base + 6 + s];
            float2 bb = sSD[base + s - 1];
            m.x += a.x - bb.x;
            m.y += a.y - bb.y;
            m.z += a.x * a.x - bb.x * bb.x;
            m.w += a.y * a.y - bb.y * bb.y;
            hmo[r * HSTR + c + s] = m;
        }
    }
    __syncthreads();

    const float d  = dr[b];
    const float C1 = (0.01f * d) * (0.01f * d);
    const float C2 = (0.03f * d) * (0.03f * d);
    const float inv_np = 1.0f / 49.0f;
    const float covh   = (49.0f / 48.0f) * 0.5f;

    // ---- Phase 3: vertical 7-tap sums, sliding over 4 output rows per
    // thread. 32 cols x 8 row-groups = 256 threads. ----
    const int c  = tid & 31;
    const int rg = tid >> 5;
    const int r  = rg * 4;
    const bool colok = (c0 + c) < OW;

    float4 v = make_float4(0.f, 0.f, 0.f, 0.f);
    #pragma unroll
    for (int k = 0; k < WIN; ++k) {
        float4 t = hmo[(r + k) * HSTR + c];
        v.x += t.x; v.y += t.y; v.z += t.z; v.w += t.w;
    }

    double acc = 0.0;
    #pragma unroll
    for (int s = 0; s < 4; ++s) {
        if (s > 0) {
            float4 a  = hmo[(r + 6 + s) * HSTR + c];
            float4 bb = hmo[(r + s - 1) * HSTR + c];
            v.x += a.x - bb.x; v.y += a.y - bb.y;
            v.z += a.z - bb.z; v.w += a.w - bb.w;
        }
        if (colok && (r0 + r + s) < OH) {
            float u_s  = v.x * inv_np, u_d  = v.y * inv_np;
            float u_ss = v.z * inv_np, u_dd = v.w * inv_np;
            float p  = u_s * u_s, q = u_d * u_d;
            float pd = p - q, ps = p + q;
            float A1 = 0.5f * pd + C1;
            float B1 = 0.5f * ps + C1;
            float A2 = covh * ((u_ss - u_dd) - pd) + C2;
            float B2 = covh * ((u_ss + u_dd) - ps) + C2;
            acc += (double)((A1 * A2) / (B1 * B2));
        }
    }

    // ---- Phase 4: block reduction of doubles ----
    for (int off = 32; off > 0; off >>= 1)
        acc += __shfl_down(acc, off, 64);
    __shared__ double sred[4];
    if ((tid & 63) == 0) sred[tid >> 6] = acc;
    __syncthreads();
    if (tid == 0) {
        partial[((size_t)blockIdx.z * NTIL + blockIdx.y) * NTIL + blockIdx.x] =
            sred[0] + sred[1] + sred[2] + sred[3];
    }
}

__global__ __launch_bounds__(512) void ssim_reduce(
    const double* __restrict__ partial, int n2, float* __restrict__ out)
{
    // n2 = number of double2 elements
    const double2* p2 = (const double2*)partial;
    double acc = 0.0;
    for (int i = threadIdx.x; i < n2; i += 512) {
        double2 v = p2[i];
        acc += v.x + v.y;
    }
    for (int off = 32; off > 0; off >>= 1)
        acc += __shfl_down(acc, off, 64);
    __shared__ double sred[8];
    if ((threadIdx.x & 63) == 0) sred[threadIdx.x >> 6] = acc;
    __syncthreads();
    if (threadIdx.x == 0) {
        double t = 0.0;
        #pragma unroll
        for (int k = 0; k < 8; ++k) t += sred[k];
        double denom = (double)NB * (double)OH * (double)OW;
        out[0] = (float)(t / denom);
    }
}

extern "C" void kernel_launch(void* const* d_in, const int* in_sizes, int n_in,
                              void* d_out, int out_size, void* d_ws, size_t ws_size,
                              hipStream_t stream) {
    const float* X  = (const float*)d_in[0];
    const float* Y  = (const float*)d_in[1];
    const float* dr = (const float*)d_in[2];
    // d_in[3] is w = ones/49; constant-folded in-kernel.
    double* partial = (double*)d_ws;   // 25600 * 8 B = 200 KB scratch

    dim3 grid(NTIL, NTIL, NB);
    ssim_partial<<<grid, 256, 0, stream>>>(X, Y, dr, partial);
    ssim_reduce<<<1, 512, 0, stream>>>(partial, (NTIL * NTIL * NB) / 2, (float*)d_out);
}

// Round 3
// 105.781 us; speedup vs baseline: 1.7030x; 1.1285x over previous
//
#include <hip/hip_runtime.h>

#define WIN    7
#define IMH    640
#define IMW    640
#define OHH    634            // IMH - WIN + 1
#define OWW    634
#define NB     64
#define NBANDS 16
#define BROWS  40             // output rows per band (15*40 + 34 = 634)
#define NTH    320            // 5 waves; 320*2 = 640 staged cols exactly
#define NPART  (NB * NBANDS)  // 1024 partials

__device__ __forceinline__ float ssim_val(float4 V, float C1, float C2,
                                          float inv_np, float covh) {
    float us  = V.x * inv_np, ud  = V.y * inv_np;
    float uss = V.z * inv_np, udd = V.w * inv_np;
    float p  = us * us, q = ud * ud;
    float pd = p - q,  ps = p + q;
    float A1 = fmaf(0.5f, pd, C1), B1 = fmaf(0.5f, ps, C1);
    float A2 = fmaf(covh, (uss - udd) - pd, C2);
    float B2 = fmaf(covh, (uss + udd) - ps, C2);
    float num = A1 * A2, den = B1 * B2;
    return num * __builtin_amdgcn_rcpf(den);
}

__global__ __launch_bounds__(NTH) void ssim_stream(
    const float* __restrict__ X, const float* __restrict__ Y,
    const float* __restrict__ dr, double* __restrict__ partial)
{
    // 7-row ring of (s,d) pairs: sbuf[u][t] = (s,d) for cols 2t, 2t+1
    __shared__ float4 sbuf[WIN][NTH];       // 7*320*16 = 35840 B -> 4 blocks/CU
    __shared__ double sred[NTH / 64];

    const int tid  = threadIdx.x;
    const int band = blockIdx.x;
    const int b    = blockIdx.y;
    const int r0   = band * BROWS;
    const int nrows = min(BROWS + WIN - 1, IMH - r0);   // 46, last band 40

    const float* Xb = X + (size_t)b * IMH * IMW;
    const float* Yb = Y + (size_t)b * IMH * IMW;

    const float drv = dr[b];
    const float C1 = (0.01f * drv) * (0.01f * drv);
    const float C2 = (0.03f * drv) * (0.03f * drv);
    const float inv_np = 1.0f / 49.0f;
    const float covh   = (49.0f / 48.0f) * 0.5f;

    // register ring of horizontal moment sums (Ss,Sd,Sss,Sdd) for 2 columns.
    // chunk height == WIN == ring size -> all indices compile-time constants.
    float4 ring0[WIN], ring1[WIN];
    #pragma unroll
    for (int u = 0; u < WIN; ++u) {
        ring0[u] = make_float4(0.f, 0.f, 0.f, 0.f);
        ring1[u] = make_float4(0.f, 0.f, 0.f, 0.f);
    }

    const bool active = (tid < 317);   // output cols 2*tid, 2*tid+1 <= 633
    double acc = 0.0;

    const int nch = (nrows + WIN - 1) / WIN;
    for (int ch = 0; ch < nch; ++ch) {
        const int base = ch * WIN;

        // ---- stage up to 7 rows: global float2 loads, (s,d) -> LDS b128 ----
        #pragma unroll
        for (int u = 0; u < WIN; ++u) {
            const int ur = base + u;
            if (ur < nrows) {
                const size_t off = (size_t)(r0 + ur) * IMW + 2 * tid;
                const float2 xv = *(const float2*)(Xb + off);
                const float2 yv = *(const float2*)(Yb + off);
                sbuf[u][tid] = make_float4(xv.x + yv.x, xv.x - yv.x,
                                           xv.y + yv.y, xv.y - yv.y);
            }
        }
        __syncthreads();

        // ---- process rows: 4 b128 taps -> h for col pair -> ring -> SSIM ----
        #pragma unroll
        for (int u = 0; u < WIN; ++u) {
            const int ur = base + u;
            if (active && ur < nrows) {
                const float4 a0 = sbuf[u][tid];
                const float4 a1 = sbuf[u][tid + 1];
                const float4 a2 = sbuf[u][tid + 2];
                const float4 a3 = sbuf[u][tid + 3];
                // shared middle sums over s1..s6 / d1..d6
                float ms  = ((a0.z + a1.x) + (a1.z + a2.x)) + (a2.z + a3.x);
                float md  = ((a0.w + a1.y) + (a1.w + a2.y)) + (a2.w + a3.y);
                float mss = fmaf(a0.z, a0.z, fmaf(a1.x, a1.x, fmaf(a1.z, a1.z,
                            fmaf(a2.x, a2.x, fmaf(a2.z, a2.z, a3.x * a3.x)))));
                float mdd = fmaf(a0.w, a0.w, fmaf(a1.y, a1.y, fmaf(a1.w, a1.w,
                            fmaf(a2.y, a2.y, fmaf(a2.w, a2.w, a3.y * a3.y)))));
                ring0[u] = make_float4(a0.x + ms, a0.y + md,
                                       fmaf(a0.x, a0.x, mss),
                                       fmaf(a0.y, a0.y, mdd));
                ring1[u] = make_float4(ms + a3.z, md + a3.w,
                                       fmaf(a3.z, a3.z, mss),
                                       fmaf(a3.w, a3.w, mdd));
                if (ur >= WIN - 1) {
                    // fresh vertical re-sum of the 7 ring rows (no drift)
                    float4 V0, V1;
                    V0.x = ((ring0[0].x + ring0[1].x) + (ring0[2].x + ring0[3].x))
                         + ((ring0[4].x + ring0[5].x) + ring0[6].x);
                    V0.y = ((ring0[0].y + ring0[1].y) + (ring0[2].y + ring0[3].y))
                         + ((ring0[4].y + ring0[5].y) + ring0[6].y);
                    V0.z = ((ring0[0].z + ring0[1].z) + (ring0[2].z + ring0[3].z))
                         + ((ring0[4].z + ring0[5].z) + ring0[6].z);
                    V0.w = ((ring0[0].w + ring0[1].w) + (ring0[2].w + ring0[3].w))
                         + ((ring0[4].w + ring0[5].w) + ring0[6].w);
                    V1.x = ((ring1[0].x + ring1[1].x) + (ring1[2].x + ring1[3].x))
                         + ((ring1[4].x + ring1[5].x) + ring1[6].x);
                    V1.y = ((ring1[0].y + ring1[1].y) + (ring1[2].y + ring1[3].y))
                         + ((ring1[4].y + ring1[5].y) + ring1[6].y);
                    V1.z = ((ring1[0].z + ring1[1].z) + (ring1[2].z + ring1[3].z))
                         + ((ring1[4].z + ring1[5].z) + ring1[6].z);
                    V1.w = ((ring1[0].w + ring1[1].w) + (ring1[2].w + ring1[3].w))
                         + ((ring1[4].w + ring1[5].w) + ring1[6].w);
                    float e0 = ssim_val(V0, C1, C2, inv_np, covh);
                    float e1 = ssim_val(V1, C1, C2, inv_np, covh);
                    acc += (double)(e0 + e1);
                }
            }
        }
        __syncthreads();
    }

    // ---- block reduction (5 waves) ----
    for (int off = 32; off > 0; off >>= 1)
        acc += __shfl_down(acc, off, 64);
    if ((tid & 63) == 0) sred[tid >> 6] = acc;
    __syncthreads();
    if (tid == 0) {
        double t = 0.0;
        #pragma unroll
        for (int k = 0; k < NTH / 64; ++k) t += sred[k];
        partial[(size_t)b * NBANDS + band] = t;
    }
}

__global__ __launch_bounds__(512) void ssim_reduce(
    const double* __restrict__ partial, int n2, float* __restrict__ out)
{
    const double2* p2 = (const double2*)partial;
    double acc = 0.0;
    for (int i = threadIdx.x; i < n2; i += 512) {
        double2 v = p2[i];
        acc += v.x + v.y;
    }
    for (int off = 32; off > 0; off >>= 1)
        acc += __shfl_down(acc, off, 64);
    __shared__ double sred[8];
    if ((threadIdx.x & 63) == 0) sred[threadIdx.x >> 6] = acc;
    __syncthreads();
    if (threadIdx.x == 0) {
        double t = 0.0;
        #pragma unroll
        for (int k = 0; k < 8; ++k) t += sred[k];
        double denom = (double)NB * (double)OHH * (double)OWW;
        out[0] = (float)(t / denom);
    }
}

extern "C" void kernel_launch(void* const* d_in, const int* in_sizes, int n_in,
                              void* d_out, int out_size, void* d_ws, size_t ws_size,
                              hipStream_t stream) {
    const float* X  = (const float*)d_in[0];
    const float* Y  = (const float*)d_in[1];
    const float* dr = (const float*)d_in[2];
    // d_in[3] is w = ones/49; constant-folded in-kernel.
    double* partial = (double*)d_ws;   // 1024 * 8 B = 8 KB scratch

    dim3 grid(NBANDS, NB);
    ssim_stream<<<grid, NTH, 0, stream>>>(X, Y, dr, partial);
    ssim_reduce<<<1, 512, 0, stream>>>(partial, NPART / 2, (float*)d_out);
}

// Round 4
// 87.215 us; speedup vs baseline: 2.0655x; 1.2129x over previous
//
#include <hip/hip_runtime.h>

#define WIN    7
#define IMH    640
#define IMW    640
#define OHH    634            // IMH - WIN + 1
#define OWW    634
#define NB     64
#define NBANDS 32
#define BROWS  20             // output rows per band (31*20 + 14 = 634)
#define NTH    320            // 5 waves; 2 output cols per thread
#define NPART  (NB * NBANDS)  // 2048 partials

__device__ __forceinline__ float ssim_val(float4 V, float C1, float C2,
                                          float inv_np, float covh) {
    float us  = V.x * inv_np, ud  = V.y * inv_np;
    float uss = V.z * inv_np, udd = V.w * inv_np;
    float p  = us * us, q = ud * ud;
    float pd = p - q,  ps = p + q;
    float A1 = fmaf(0.5f, pd, C1), B1 = fmaf(0.5f, ps, C1);
    float A2 = fmaf(covh, (uss - udd) - pd, C2);
    float B2 = fmaf(covh, (uss + udd) - ps, C2);
    return (A1 * A2) * __builtin_amdgcn_rcpf(B1 * B2);
}

__global__ __launch_bounds__(NTH, 4) void ssim_stream(
    const float* __restrict__ X, const float* __restrict__ Y,
    const float* __restrict__ dr, double* __restrict__ partial)
{
    __shared__ double sred[NTH / 64];

    const int tid  = threadIdx.x;
    const int band = blockIdx.x;
    const int b    = blockIdx.y;
    const int r0   = band * BROWS;
    const int nrows = min(BROWS + WIN - 1, IMH - r0);   // 26; last band 20

    // thread covers output cols 2t,2t+1; loads cols 2t..2t+7.
    // threads 317..319 have no valid outputs: clamp to a duplicate load
    // (L1 hits) and mask their accumulation.
    const int  cbase  = min(2 * tid, IMW - 8);
    const bool active = (tid < 317);

    const size_t ioff = (size_t)b * IMH * IMW + (size_t)r0 * IMW + cbase;
    const float* Xp = X + ioff;
    const float* Yp = Y + ioff;

    const float drv = dr[b];
    const float C1 = (0.01f * drv) * (0.01f * drv);
    const float C2 = (0.03f * drv) * (0.03f * drv);
    const float inv_np = 1.0f / 49.0f;
    const float covh   = (49.0f / 48.0f) * 0.5f;

    // 7-slot register ring of horizontal moment sums (Ss,Sd,Sss,Sdd) per col.
    // Zero-init makes the first 6 rows a natural warm-up for the running V.
    float4 ring0[WIN], ring1[WIN];
    #pragma unroll
    for (int u = 0; u < WIN; ++u) {
        ring0[u] = make_float4(0.f, 0.f, 0.f, 0.f);
        ring1[u] = make_float4(0.f, 0.f, 0.f, 0.f);
    }
    float4 V0 = make_float4(0.f, 0.f, 0.f, 0.f);
    float4 V1 = make_float4(0.f, 0.f, 0.f, 0.f);

    double acc = 0.0;

    // rows unrolled by 7 so ring slot == u is compile-time (rule #20).
    for (int ch = 0; ch < 4; ++ch) {
        const int base = ch * WIN;
        #pragma unroll
        for (int u = 0; u < WIN; ++u) {
            const int ur = base + u;
            if (ur < nrows) {                       // wave-uniform branch
                const size_t off = (size_t)ur * IMW;
                const float4 xa = *(const float4*)(Xp + off);
                const float4 xb = *(const float4*)(Xp + off + 4);
                const float4 ya = *(const float4*)(Yp + off);
                const float4 yb = *(const float4*)(Yp + off + 4);

                const float4 sa = make_float4(xa.x + ya.x, xa.y + ya.y,
                                              xa.z + ya.z, xa.w + ya.w);
                const float4 sb = make_float4(xb.x + yb.x, xb.y + yb.y,
                                              xb.z + yb.z, xb.w + yb.w);
                const float4 da = make_float4(xa.x - ya.x, xa.y - ya.y,
                                              xa.z - ya.z, xa.w - ya.w);
                const float4 db = make_float4(xb.x - yb.x, xb.y - yb.y,
                                              xb.z - yb.z, xb.w - yb.w);

                // horizontal 7-tap sums for the two output cols
                const float hs0 = ((sa.x + sa.y) + (sa.z + sa.w))
                                + ((sb.x + sb.y) + sb.z);
                const float hs1 = (hs0 - sa.x) + sb.w;
                const float hd0 = ((da.x + da.y) + (da.z + da.w))
                                + ((db.x + db.y) + db.z);
                const float hd1 = (hd0 - da.x) + db.w;
                const float hss0 = fmaf(sa.x, sa.x, fmaf(sa.y, sa.y,
                                   fmaf(sa.z, sa.z, fmaf(sa.w, sa.w,
                                   fmaf(sb.x, sb.x, fmaf(sb.y, sb.y,
                                        sb.z * sb.z))))));
                const float hss1 = fmaf(sb.w, sb.w, hss0 - sa.x * sa.x);
                const float hdd0 = fmaf(da.x, da.x, fmaf(da.y, da.y,
                                   fmaf(da.z, da.z, fmaf(da.w, da.w,
                                   fmaf(db.x, db.x, fmaf(db.y, db.y,
                                        db.z * db.z))))));
                const float hdd1 = fmaf(db.w, db.w, hdd0 - da.x * da.x);

                // running vertical sums: V += h_new - h[row-7] (ring slot u)
                V0.x += hs0  - ring0[u].x;  V0.y += hd0  - ring0[u].y;
                V0.z += hss0 - ring0[u].z;  V0.w += hdd0 - ring0[u].w;
                V1.x += hs1  - ring1[u].x;  V1.y += hd1  - ring1[u].y;
                V1.z += hss1 - ring1[u].z;  V1.w += hdd1 - ring1[u].w;
                ring0[u] = make_float4(hs0, hd0, hss0, hdd0);
                ring1[u] = make_float4(hs1, hd1, hss1, hdd1);

                if (active && ur >= WIN - 1) {
                    const float e0 = ssim_val(V0, C1, C2, inv_np, covh);
                    const float e1 = ssim_val(V1, C1, C2, inv_np, covh);
                    acc += (double)(e0 + e1);
                }
            }
        }
    }

    // ---- block reduction (5 waves) ----
    for (int off = 32; off > 0; off >>= 1)
        acc += __shfl_down(acc, off, 64);
    if ((tid & 63) == 0) sred[tid >> 6] = acc;
    __syncthreads();
    if (tid == 0) {
        double t = 0.0;
        #pragma unroll
        for (int k = 0; k < NTH / 64; ++k) t += sred[k];
        partial[(size_t)b * NBANDS + band] = t;
    }
}

__global__ __launch_bounds__(512) void ssim_reduce(
    const double* __restrict__ partial, int n2, float* __restrict__ out)
{
    const double2* p2 = (const double2*)partial;
    double acc = 0.0;
    for (int i = threadIdx.x; i < n2; i += 512) {
        double2 v = p2[i];
        acc += v.x + v.y;
    }
    for (int off = 32; off > 0; off >>= 1)
        acc += __shfl_down(acc, off, 64);
    __shared__ double sred[8];
    if ((threadIdx.x & 63) == 0) sred[threadIdx.x >> 6] = acc;
    __syncthreads();
    if (threadIdx.x == 0) {
        double t = 0.0;
        #pragma unroll
        for (int k = 0; k < 8; ++k) t += sred[k];
        double denom = (double)NB * (double)OHH * (double)OWW;
        out[0] = (float)(t / denom);
    }
}

extern "C" void kernel_launch(void* const* d_in, const int* in_sizes, int n_in,
                              void* d_out, int out_size, void* d_ws, size_t ws_size,
                              hipStream_t stream) {
    const float* X  = (const float*)d_in[0];
    const float* Y  = (const float*)d_in[1];
    const float* dr = (const float*)d_in[2];
    // d_in[3] is w = ones/49; constant-folded in-kernel.
    double* partial = (double*)d_ws;   // 2048 * 8 B = 16 KB scratch

    dim3 grid(NBANDS, NB);
    ssim_stream<<<grid, NTH, 0, stream>>>(X, Y, dr, partial);
    ssim_reduce<<<1, 512, 0, stream>>>(partial, NPART / 2, (float*)d_out);
}